// Round 3
// baseline (515.331 us; speedup 1.0000x reference)
//
#include <hip/hip_runtime.h>
#include <hip/hip_bf16.h>

// Problem constants
#define B_   2
#define LQ_  2048
#define NH_  8
#define HB_  16      // NH_*B_
#define DM_  512
#define DK_  64

// 1/sqrt(512)  (temper = sqrt(d_model), per reference)
#define INV_TEMPER 0.04419417382415922f

// ---------------------------------------------------------------------------
// K1: per-head projections  x(b,l,512) @ w(h,512,64) -> out[(h*B+b)][l][64] fp32
// 8 rows per block, 128 threads, each thread owns 4 consecutive k of one head.
// ---------------------------------------------------------------------------
__global__ __launch_bounds__(128) void qkv_proj(
    const float* __restrict__ qx, const float* __restrict__ kx, const float* __restrict__ vx,
    const float* __restrict__ wq, const float* __restrict__ wk, const float* __restrict__ wv,
    float* __restrict__ qh, float* __restrict__ kh, float* __restrict__ vh){
  const int which = blockIdx.y;
  const float* x = (which == 0) ? qx : (which == 1) ? kx : vx;
  const float* w = (which == 0) ? wq : (which == 1) ? wk : wv;
  float* out     = (which == 0) ? qh : (which == 1) ? kh : vh;

  const int row0 = blockIdx.x * 8;           // 8 (b,l) rows per block
  const int tid  = threadIdx.x;
  __shared__ float xs[8][512];

  // stage 8 input rows
  const float4* xv = (const float4*)(x + (long)row0 * DM_);
  for (int i = tid; i < 8 * (DM_/4); i += 128){
    float4 t = xv[i];
    int r = i >> 7, c = (i & 127) * 4;
    xs[r][c+0] = t.x; xs[r][c+1] = t.y; xs[r][c+2] = t.z; xs[r][c+3] = t.w;
  }
  __syncthreads();

  const int o  = tid * 4;          // 512 outputs / 128 threads
  const int h  = o >> 6;
  const int kk = o & 63;
  const float* wp = w + (long)h * DM_ * DK_ + kk;

  float acc[8][4];
  #pragma unroll
  for (int r = 0; r < 8; ++r){ acc[r][0]=0.f; acc[r][1]=0.f; acc[r][2]=0.f; acc[r][3]=0.f; }

  for (int d = 0; d < DM_; ++d){
    float4 wv4 = *(const float4*)(wp + (long)d * DK_);
    #pragma unroll
    for (int r = 0; r < 8; ++r){
      float xd = xs[r][d];
      acc[r][0] += xd * wv4.x; acc[r][1] += xd * wv4.y;
      acc[r][2] += xd * wv4.z; acc[r][3] += xd * wv4.w;
    }
  }

  #pragma unroll
  for (int r = 0; r < 8; ++r){
    int row = row0 + r;
    int b = row >> 11, l = row & 2047;
    float* op = out + (((long)h * B_ + b) * LQ_ + l) * DK_ + kk;
    op[0] = acc[r][0]; op[1] = acc[r][1]; op[2] = acc[r][2]; op[3] = acc[r][3];
  }
}

// ---------------------------------------------------------------------------
// K2: fused scores + online top-1 softmax stats.
// Block: 256 thr, 64 q-rows x all 2048 j in 64-wide tiles.
// Thread (tid>>4, tid&15): rows rt+16i, cols ct+16j.
// Outputs per row: pmax = 1/sum_exp(s - smax), amax = argmax index.
// ---------------------------------------------------------------------------
__global__ __launch_bounds__(256) void attn_top1(
    const float* __restrict__ qh, const float* __restrict__ kh,
    float* __restrict__ pmax, int* __restrict__ amax){
  const int hb = blockIdx.x;
  const int q0 = blockIdx.y * 64;
  const int tid = threadIdx.x;
  __shared__ float qs[64][68];
  __shared__ float ks[64][68];

  // stage q tile
  const float* qbase = qh + ((long)hb * LQ_ + q0) * DK_;
  for (int i = tid; i < 64 * 16; i += 256){
    int r = i >> 4, c4 = (i & 15) * 4;
    float4 v = *(const float4*)(qbase + r * 64 + c4);
    qs[r][c4] = v.x; qs[r][c4+1] = v.y; qs[r][c4+2] = v.z; qs[r][c4+3] = v.w;
  }

  const int rt = tid >> 4;   // row base: rows rt + 16*i
  const int ct = tid & 15;   // col base: cols ct + 16*j

  float m[4], sum[4]; int arg[4];
  #pragma unroll
  for (int i = 0; i < 4; ++i){ m[i] = -1e30f; sum[i] = 0.f; arg[i] = 0; }

  for (int jt = 0; jt < LQ_ / 64; ++jt){
    __syncthreads();
    const float* kbase = kh + ((long)hb * LQ_ + jt * 64) * DK_;
    for (int i = tid; i < 64 * 16; i += 256){
      int r = i >> 4, c4 = (i & 15) * 4;
      float4 v = *(const float4*)(kbase + r * 64 + c4);
      ks[r][c4] = v.x; ks[r][c4+1] = v.y; ks[r][c4+2] = v.z; ks[r][c4+3] = v.w;
    }
    __syncthreads();

    float acc[4][4];
    #pragma unroll
    for (int i = 0; i < 4; ++i)
      #pragma unroll
      for (int j = 0; j < 4; ++j) acc[i][j] = 0.f;

    for (int k = 0; k < 64; k += 4){
      float4 a[4], b[4];
      #pragma unroll
      for (int i = 0; i < 4; ++i) a[i] = *(const float4*)&qs[rt + 16*i][k];
      #pragma unroll
      for (int j = 0; j < 4; ++j) b[j] = *(const float4*)&ks[ct + 16*j][k];
      #pragma unroll
      for (int i = 0; i < 4; ++i)
        #pragma unroll
        for (int j = 0; j < 4; ++j)
          acc[i][j] += a[i].x*b[j].x + a[i].y*b[j].y + a[i].z*b[j].z + a[i].w*b[j].w;
    }

    #pragma unroll
    for (int i = 0; i < 4; ++i){
      #pragma unroll
      for (int j = 0; j < 4; ++j){
        float s = acc[i][j] * INV_TEMPER;
        int jg = jt * 64 + ct + 16 * j;
        if (s > m[i]){
          sum[i] = sum[i] * __expf(m[i] - s) + 1.f;
          m[i] = s; arg[i] = jg;
        } else {
          sum[i] += __expf(s - m[i]);
        }
      }
    }
  }

  // merge the 16 lanes (ct = 0..15) that share each row group
  #pragma unroll
  for (int off = 1; off < 16; off <<= 1){
    #pragma unroll
    for (int i = 0; i < 4; ++i){
      float m2 = __shfl_xor(m[i], off);
      float s2 = __shfl_xor(sum[i], off);
      int   a2 = __shfl_xor(arg[i], off);
      float mn = fmaxf(m[i], m2);
      sum[i] = sum[i] * __expf(m[i] - mn) + s2 * __expf(m2 - mn);
      arg[i] = (m2 > m[i]) ? a2 : ((m2 == m[i]) ? (arg[i] < a2 ? arg[i] : a2) : arg[i]);
      m[i] = mn;
    }
  }

  if (ct == 0){
    #pragma unroll
    for (int i = 0; i < 4; ++i){
      long row = (long)hb * LQ_ + q0 + rt + 16 * i;
      pmax[row] = 1.0f / sum[i];
      amax[row] = arg[i];
    }
  }
}

// ---------------------------------------------------------------------------
// K3: gather out_heads rows = pmax * vh[argmax]
// One wave per (hb,q) row.
// ---------------------------------------------------------------------------
__global__ __launch_bounds__(256) void gather_oh(
    const float* __restrict__ vh, const float* __restrict__ pmax, const int* __restrict__ amax,
    float* __restrict__ oh){
  int row  = blockIdx.x * 4 + (threadIdx.x >> 6);
  int lane = threadIdx.x & 63;
  int hb = row >> 11, q = row & 2047;
  int h = hb >> 1, b = hb & 1;
  float p = pmax[row];
  int a = amax[row];
  float val = vh[((long)hb * LQ_ + a) * DK_ + lane];
  oh[((long)(b * LQ_ + q)) * DM_ + h * DK_ + lane] = p * val;
}

// ---------------------------------------------------------------------------
// K4: transpose fp32 weight [R][C] -> [C][R]  (once, tiny)
// ---------------------------------------------------------------------------
__global__ void transpose_w(const float* __restrict__ in, float* __restrict__ out, int R, int C){
  long i = (long)blockIdx.x * blockDim.x + threadIdx.x;
  if (i < (long)R * C){
    int r = (int)(i / C), c = (int)(i % C);
    out[(long)c * R + r] = in[i];
  }
}

// ---------------------------------------------------------------------------
// K5: y = oh @ proj_w.T + proj_b  using transposed weights wt[in][out]
// ---------------------------------------------------------------------------
__global__ __launch_bounds__(128) void proj_kernel(
    const float* __restrict__ oh, const float* __restrict__ wt,
    const float* __restrict__ pb, float* __restrict__ y){
  const int row0 = blockIdx.x * 8;
  const int tid  = threadIdx.x;
  __shared__ float xs[8][512];
  const float4* src = (const float4*)(oh + (long)row0 * DM_);
  for (int i = tid; i < 8 * (DM_/4); i += 128){
    float4 v = src[i];
    int r = i >> 7, c = (i & 127) * 4;
    xs[r][c] = v.x; xs[r][c+1] = v.y; xs[r][c+2] = v.z; xs[r][c+3] = v.w;
  }
  __syncthreads();

  const int o = tid * 4;
  float acc[8][4];
  float b0 = pb[o], b1 = pb[o+1], b2 = pb[o+2], b3 = pb[o+3];
  #pragma unroll
  for (int r = 0; r < 8; ++r){ acc[r][0]=b0; acc[r][1]=b1; acc[r][2]=b2; acc[r][3]=b3; }

  for (int d = 0; d < DM_; ++d){
    float4 wv = *(const float4*)(wt + (long)d * DM_ + o);
    #pragma unroll
    for (int r = 0; r < 8; ++r){
      float xd = xs[r][d];
      acc[r][0] += xd * wv.x; acc[r][1] += xd * wv.y;
      acc[r][2] += xd * wv.z; acc[r][3] += xd * wv.w;
    }
  }
  #pragma unroll
  for (int r = 0; r < 8; ++r){
    float* yp = y + (long)(row0 + r) * DM_ + o;
    yp[0]=acc[r][0]; yp[1]=acc[r][1]; yp[2]=acc[r][2]; yp[3]=acc[r][3];
  }
}

// ---------------------------------------------------------------------------
// K6: out = [q, y] @ lin_w.T + lin_b.  wt[d][n], d in 0..1023.
// ---------------------------------------------------------------------------
__global__ __launch_bounds__(128) void lin_kernel(
    const float* __restrict__ qin, const float* __restrict__ y,
    const float* __restrict__ wt, const float* __restrict__ lb,
    float* __restrict__ out){
  const int row0 = blockIdx.x * 8;
  const int tid  = threadIdx.x;
  __shared__ float xs[8][1024];

  // first 512 of each row: q, next 512: y
  const float4* qv = (const float4*)(qin + (long)row0 * DM_);
  for (int i = tid; i < 8 * (DM_/4); i += 128){
    float4 v = qv[i];
    int r = i >> 7, c = (i & 127) * 4;
    xs[r][c] = v.x; xs[r][c+1] = v.y; xs[r][c+2] = v.z; xs[r][c+3] = v.w;
  }
  const float4* yv = (const float4*)(y + (long)row0 * DM_);
  for (int i = tid; i < 8 * (DM_/4); i += 128){
    float4 v = yv[i];
    int r = i >> 7, c = (i & 127) * 4;
    xs[r][512+c] = v.x; xs[r][512+c+1] = v.y; xs[r][512+c+2] = v.z; xs[r][512+c+3] = v.w;
  }
  __syncthreads();

  const int o = tid * 4;
  float acc[8][4];
  float b0 = lb[o], b1 = lb[o+1], b2 = lb[o+2], b3 = lb[o+3];
  #pragma unroll
  for (int r = 0; r < 8; ++r){ acc[r][0]=b0; acc[r][1]=b1; acc[r][2]=b2; acc[r][3]=b3; }

  for (int d = 0; d < 2 * DM_; ++d){
    float4 wv = *(const float4*)(wt + (long)d * DM_ + o);
    #pragma unroll
    for (int r = 0; r < 8; ++r){
      float xd = xs[r][d];
      acc[r][0] += xd * wv.x; acc[r][1] += xd * wv.y;
      acc[r][2] += xd * wv.z; acc[r][3] += xd * wv.w;
    }
  }
  #pragma unroll
  for (int r = 0; r < 8; ++r){
    float* op = out + (long)(row0 + r) * DM_ + o;
    op[0]=acc[r][0]; op[1]=acc[r][1]; op[2]=acc[r][2]; op[3]=acc[r][3];
  }
}

// ---------------------------------------------------------------------------
// K7: fused zero + scatter of the attn output region (runs LAST).
// One wave per (hb,q) row: 2048 floats = 512 float4 per row; the float4
// covering column amax carries the p value.
// ---------------------------------------------------------------------------
__global__ __launch_bounds__(256) void write_attn(
    const float* __restrict__ pmax, const int* __restrict__ amax,
    float* __restrict__ attn_out){
  int row  = blockIdx.x * 4 + (threadIdx.x >> 6);
  int lane = threadIdx.x & 63;
  float p = pmax[row];
  int a = amax[row];
  float4* rowp = (float4*)(attn_out + (long)row * LQ_);
  #pragma unroll
  for (int i = 0; i < 8; ++i){
    int f4idx = i * 64 + lane;        // 512 float4s per row
    int col0  = f4idx * 4;
    float4 z = make_float4(0.f, 0.f, 0.f, 0.f);
    if (a >= col0 && a < col0 + 4){
      int r = a - col0;               // 0..3
      if      (r == 0) z.x = p;
      else if (r == 1) z.y = p;
      else if (r == 2) z.z = p;
      else             z.w = p;
    }
    rowp[f4idx] = z;
  }
}

// ---------------------------------------------------------------------------
extern "C" void kernel_launch(void* const* d_in, const int* in_sizes, int n_in,
                              void* d_out, int out_size, void* d_ws, size_t ws_size,
                              hipStream_t stream){
  const float* q  = (const float*)d_in[0];
  const float* k  = (const float*)d_in[1];
  const float* v  = (const float*)d_in[2];
  const float* wq = (const float*)d_in[3];
  const float* wk = (const float*)d_in[4];
  const float* wv = (const float*)d_in[5];
  const float* pw = (const float*)d_in[6];
  const float* pb = (const float*)d_in[7];
  const float* lw = (const float*)d_in[8];
  const float* lb = (const float*)d_in[9];

  float* out0     = (float*)d_out;                    // (2,2048,512)
  float* attn_out = out0 + (long)B_ * LQ_ * DM_;      // (16,2048,2048) = 67.1M floats

  // Large scratch lives INSIDE the attn output region (67.1M floats available;
  // we use ~11.3M). It is dead before write_attn rewrites the region.
  float* scr  = attn_out;
  float* qh   = scr;                                  // 16*2048*64
  float* kh   = qh + (long)HB_ * LQ_ * DK_;
  float* vh   = kh + (long)HB_ * LQ_ * DK_;
  float* oh   = vh + (long)HB_ * LQ_ * DK_;           // 2*2048*512
  float* y    = oh + (long)B_ * LQ_ * DM_;            // 2*2048*512
  float* pwT  = y  + (long)B_ * LQ_ * DM_;            // 512*512
  float* lwT  = pwT + (long)DM_ * DM_;                // 1024*512
  // total = 11,272,192 floats = 43 MB << 268 MB region

  // d_ws: only the tiny per-row stats (256 KB) — must survive write_attn.
  float* pmax = (float*)d_ws;                         // 16*2048 floats
  int*   amax = (int*)(pmax + (long)HB_ * LQ_);       // 16*2048 ints

  // weight transposes ([out][in] -> [in][out])
  transpose_w<<<(DM_*DM_ + 255)/256, 256, 0, stream>>>(pw, pwT, DM_, DM_);
  transpose_w<<<(DM_*2*DM_ + 255)/256, 256, 0, stream>>>(lw, lwT, DM_, 2*DM_);

  // per-head projections
  qkv_proj<<<dim3(B_*LQ_/8, 3), 128, 0, stream>>>(q, k, v, wq, wk, wv, qh, kh, vh);

  // fused scores + top-1 online softmax
  attn_top1<<<dim3(HB_, LQ_/64), 256, 0, stream>>>(qh, kh, pmax, amax);

  // gather PV rows
  gather_oh<<<HB_*LQ_/4, 256, 0, stream>>>(vh, pmax, amax, oh);

  // output projection
  proj_kernel<<<B_*LQ_/8, 128, 0, stream>>>(oh, pwT, pb, y);

  // final concat-linear -> output 0
  lin_kernel<<<B_*LQ_/8, 128, 0, stream>>>(q, y, lwT, lb, out0);

  // LAST: rewrite the whole attn region with zeros + scattered p values
  write_attn<<<HB_*LQ_/4, 256, 0, stream>>>(pmax, amax, attn_out);
}

// Round 4
// 356.419 us; speedup vs baseline: 1.4459x; 1.4459x over previous
//
#include <hip/hip_runtime.h>
#include <hip/hip_bf16.h>

// Problem constants
#define B_   2
#define LQ_  2048
#define NH_  8
#define HB_  16      // NH_*B_
#define DM_  512
#define DK_  64

// 1/sqrt(512)  (temper = sqrt(d_model), per reference)
#define INV_TEMPER 0.04419417382415922f
// folded into Q at projection time: scores come out of MFMA in log2-space
#define SCALE_T (0.04419417382415922f * 1.4426950408889634f)

typedef short s16x8 __attribute__((ext_vector_type(8)));   // 8 bf16 (4 VGPRs)
typedef float f32x4 __attribute__((ext_vector_type(4)));   // MFMA 16x16 C/D

__device__ __forceinline__ ushort f2bfbits(float f){
  __hip_bfloat16 h = __float2bfloat16(f);
  union { __hip_bfloat16 h; ushort u; } cv; cv.h = h; return cv.u;
}

// ---------------------------------------------------------------------------
// K1: per-head projections  x(b,l,512) @ w(h,512,64).
// which=0 -> qhb (bf16, pre-scaled by SCALE_T), which=1 -> khb (bf16),
// which=2 -> vh (fp32).
// 8 rows per block, 128 threads, each thread owns 4 consecutive k of one head.
// ---------------------------------------------------------------------------
__global__ __launch_bounds__(128) void qkv_proj(
    const float* __restrict__ qx, const float* __restrict__ kx, const float* __restrict__ vx,
    const float* __restrict__ wq, const float* __restrict__ wk, const float* __restrict__ wv,
    ushort* __restrict__ qhb, ushort* __restrict__ khb, float* __restrict__ vh){
  const int which = blockIdx.y;
  const float* x = (which == 0) ? qx : (which == 1) ? kx : vx;
  const float* w = (which == 0) ? wq : (which == 1) ? wk : wv;

  const int row0 = blockIdx.x * 8;           // 8 (b,l) rows per block
  const int tid  = threadIdx.x;
  __shared__ float xs[8][512];

  // stage 8 input rows
  const float4* xv = (const float4*)(x + (long)row0 * DM_);
  for (int i = tid; i < 8 * (DM_/4); i += 128){
    float4 t = xv[i];
    int r = i >> 7, c = (i & 127) * 4;
    xs[r][c+0] = t.x; xs[r][c+1] = t.y; xs[r][c+2] = t.z; xs[r][c+3] = t.w;
  }
  __syncthreads();

  const int o  = tid * 4;          // 512 outputs / 128 threads
  const int h  = o >> 6;
  const int kk = o & 63;
  const float* wp = w + (long)h * DM_ * DK_ + kk;

  float acc[8][4];
  #pragma unroll
  for (int r = 0; r < 8; ++r){ acc[r][0]=0.f; acc[r][1]=0.f; acc[r][2]=0.f; acc[r][3]=0.f; }

  for (int d = 0; d < DM_; ++d){
    float4 wv4 = *(const float4*)(wp + (long)d * DK_);
    #pragma unroll
    for (int r = 0; r < 8; ++r){
      float xd = xs[r][d];
      acc[r][0] += xd * wv4.x; acc[r][1] += xd * wv4.y;
      acc[r][2] += xd * wv4.z; acc[r][3] += xd * wv4.w;
    }
  }

  if (which == 2){
    #pragma unroll
    for (int r = 0; r < 8; ++r){
      int row = row0 + r;
      int b = row >> 11, l = row & 2047;
      float* op = vh + (((long)h * B_ + b) * LQ_ + l) * DK_ + kk;
      op[0] = acc[r][0]; op[1] = acc[r][1]; op[2] = acc[r][2]; op[3] = acc[r][3];
    }
  } else {
    const float sc = (which == 0) ? SCALE_T : 1.0f;
    ushort* dst = (which == 0) ? qhb : khb;
    #pragma unroll
    for (int r = 0; r < 8; ++r){
      int row = row0 + r;
      int b = row >> 11, l = row & 2047;
      ushort4 u;
      u.x = f2bfbits(acc[r][0] * sc); u.y = f2bfbits(acc[r][1] * sc);
      u.z = f2bfbits(acc[r][2] * sc); u.w = f2bfbits(acc[r][3] * sc);
      *(ushort4*)(dst + (((long)h * B_ + b) * LQ_ + l) * DK_ + kk) = u;
    }
  }
}

// ---------------------------------------------------------------------------
// K2: MFMA scores + branch-free top-1 softmax stats (log2-space).
// Block: 256 thr = 4 waves; block owns 64 q-rows x all 2048 j.
// Wave w owns q-rows [w*16, w*16+16); Q frags in registers (loaded once).
// K tile 64x64 bf16 staged in LDS with XOR swizzle (byte ^= (row&7)<<4).
// acc from MFMA = t = s*log2e (Q pre-scaled). sum += 2^t directly (|s|<~6,
// no overflow), max/argmax via cmp+sel. pmax = 2^m / sum.
// C layout (16x16): col=lane&15, row=(lane>>4)*4+reg.
// A/B frag: idx=lane&15, k=(lane>>4)*8 + 0..7 (8 contiguous bf16).
// ---------------------------------------------------------------------------
__global__ __launch_bounds__(256) void attn_top1_mfma(
    const ushort* __restrict__ qhb, const ushort* __restrict__ khb,
    float* __restrict__ pmax, int* __restrict__ amax){
  const int hb  = blockIdx.x;
  const int q0  = blockIdx.y * 64;
  const int tid = threadIdx.x;
  const int wid  = tid >> 6;
  const int lane = tid & 63;
  const int l15  = lane & 15;
  const int l4   = lane >> 4;

  __shared__ ushort ks[64 * 64];   // 8 KB, swizzled rows of 128B

  // Q fragments (registers): rows q0 + wid*16 + l15, k = l4*8.. (2 k-steps)
  const ushort* qrow = qhb + ((long)hb * LQ_ + q0 + wid * 16 + l15) * DK_;
  s16x8 aq0 = *(const s16x8*)(qrow +  0 + l4 * 8);
  s16x8 aq1 = *(const s16x8*)(qrow + 32 + l4 * 8);

  float m[4], sum[4]; int arg[4];
  #pragma unroll
  for (int r = 0; r < 4; ++r){ m[r] = -1e30f; sum[r] = 0.f; arg[r] = 0; }

  for (int jt = 0; jt < LQ_ / 64; ++jt){
    __syncthreads();   // protect previous tile's reads
    // stage K tile (64 rows x 64 bf16 = 128B/row), swizzled
    const ushort* kbase = khb + ((long)hb * LQ_ + jt * 64) * DK_;
    #pragma unroll
    for (int i = tid; i < 512; i += 256){
      int r = i >> 3, c = i & 7;
      uint4 val = *(const uint4*)(kbase + r * 64 + c * 8);
      *(uint4*)((char*)ks + r * 128 + ((c * 16) ^ ((r & 7) << 4))) = val;
    }
    __syncthreads();

    f32x4 acc[4];
    #pragma unroll
    for (int ct = 0; ct < 4; ++ct){
      int row = ct * 16 + l15;                 // K-row (score col) in tile
      const char* base = (const char*)ks + row * 128;
      int swz = (row & 7) << 4;
      s16x8 b0 = *(const s16x8*)(base + ((l4 * 16) ^ swz));
      s16x8 b1 = *(const s16x8*)(base + ((64 + l4 * 16) ^ swz));
      f32x4 c; c[0]=0.f; c[1]=0.f; c[2]=0.f; c[3]=0.f;
      c = __builtin_amdgcn_mfma_f32_16x16x32_bf16(aq0, b0, c, 0, 0, 0);
      c = __builtin_amdgcn_mfma_f32_16x16x32_bf16(aq1, b1, c, 0, 0, 0);
      acc[ct] = c;
    }

    // branch-free top-1 softmax update (log2-space, absolute sums)
    #pragma unroll
    for (int ct = 0; ct < 4; ++ct){
      int col = jt * 64 + ct * 16 + l15;
      #pragma unroll
      for (int r = 0; r < 4; ++r){
        float t = acc[ct][r];
        sum[r] += exp2f(t);
        bool gt = t > m[r];
        arg[r] = gt ? col : arg[r];
        m[r]   = gt ? t : m[r];
      }
    }
  }

  // merge across the 16 lanes (l15) sharing each row; sums are absolute -> add
  #pragma unroll
  for (int off = 1; off < 16; off <<= 1){
    #pragma unroll
    for (int r = 0; r < 4; ++r){
      float m2 = __shfl_xor(m[r], off);
      float s2 = __shfl_xor(sum[r], off);
      int   a2 = __shfl_xor(arg[r], off);
      sum[r] += s2;
      bool take = (m2 > m[r]) || (m2 == m[r] && a2 < arg[r]);
      arg[r] = take ? a2 : arg[r];
      m[r]   = take ? m2 : m[r];
    }
  }

  if (l15 == 0){
    #pragma unroll
    for (int r = 0; r < 4; ++r){
      long row = (long)hb * LQ_ + q0 + wid * 16 + l4 * 4 + r;
      pmax[row] = exp2f(m[r]) / sum[r];
      amax[row] = arg[r];
    }
  }
}

// ---------------------------------------------------------------------------
// K3: gather out_heads rows = pmax * vh[argmax]
// ---------------------------------------------------------------------------
__global__ __launch_bounds__(256) void gather_oh(
    const float* __restrict__ vh, const float* __restrict__ pmax, const int* __restrict__ amax,
    float* __restrict__ oh){
  int row  = blockIdx.x * 4 + (threadIdx.x >> 6);
  int lane = threadIdx.x & 63;
  int hb = row >> 11, q = row & 2047;
  int h = hb >> 1, b = hb & 1;
  float p = pmax[row];
  int a = amax[row];
  float val = vh[((long)hb * LQ_ + a) * DK_ + lane];
  oh[((long)(b * LQ_ + q)) * DM_ + h * DK_ + lane] = p * val;
}

// ---------------------------------------------------------------------------
// K4: transpose fp32 weight [R][C] -> [C][R]  (once, tiny)
// ---------------------------------------------------------------------------
__global__ void transpose_w(const float* __restrict__ in, float* __restrict__ out, int R, int C){
  long i = (long)blockIdx.x * blockDim.x + threadIdx.x;
  if (i < (long)R * C){
    int r = (int)(i / C), c = (int)(i % C);
    out[(long)c * R + r] = in[i];
  }
}

// ---------------------------------------------------------------------------
// K5: y = oh @ proj_w.T + proj_b  using transposed weights wt[in][out]
// ---------------------------------------------------------------------------
__global__ __launch_bounds__(128) void proj_kernel(
    const float* __restrict__ oh, const float* __restrict__ wt,
    const float* __restrict__ pb, float* __restrict__ y){
  const int row0 = blockIdx.x * 8;
  const int tid  = threadIdx.x;
  __shared__ float xs[8][512];
  const float4* src = (const float4*)(oh + (long)row0 * DM_);
  for (int i = tid; i < 8 * (DM_/4); i += 128){
    float4 v = src[i];
    int r = i >> 7, c = (i & 127) * 4;
    xs[r][c] = v.x; xs[r][c+1] = v.y; xs[r][c+2] = v.z; xs[r][c+3] = v.w;
  }
  __syncthreads();

  const int o = tid * 4;
  float acc[8][4];
  float b0 = pb[o], b1 = pb[o+1], b2 = pb[o+2], b3 = pb[o+3];
  #pragma unroll
  for (int r = 0; r < 8; ++r){ acc[r][0]=b0; acc[r][1]=b1; acc[r][2]=b2; acc[r][3]=b3; }

  for (int d = 0; d < DM_; ++d){
    float4 wv = *(const float4*)(wt + (long)d * DM_ + o);
    #pragma unroll
    for (int r = 0; r < 8; ++r){
      float xd = xs[r][d];
      acc[r][0] += xd * wv.x; acc[r][1] += xd * wv.y;
      acc[r][2] += xd * wv.z; acc[r][3] += xd * wv.w;
    }
  }
  #pragma unroll
  for (int r = 0; r < 8; ++r){
    float* yp = y + (long)(row0 + r) * DM_ + o;
    yp[0]=acc[r][0]; yp[1]=acc[r][1]; yp[2]=acc[r][2]; yp[3]=acc[r][3];
  }
}

// ---------------------------------------------------------------------------
// K6: out = [q, y] @ lin_w.T + lin_b.  wt[d][n], d in 0..1023.
// ---------------------------------------------------------------------------
__global__ __launch_bounds__(128) void lin_kernel(
    const float* __restrict__ qin, const float* __restrict__ y,
    const float* __restrict__ wt, const float* __restrict__ lb,
    float* __restrict__ out){
  const int row0 = blockIdx.x * 8;
  const int tid  = threadIdx.x;
  __shared__ float xs[8][1024];

  const float4* qv = (const float4*)(qin + (long)row0 * DM_);
  for (int i = tid; i < 8 * (DM_/4); i += 128){
    float4 v = qv[i];
    int r = i >> 7, c = (i & 127) * 4;
    xs[r][c] = v.x; xs[r][c+1] = v.y; xs[r][c+2] = v.z; xs[r][c+3] = v.w;
  }
  const float4* yv = (const float4*)(y + (long)row0 * DM_);
  for (int i = tid; i < 8 * (DM_/4); i += 128){
    float4 v = yv[i];
    int r = i >> 7, c = (i & 127) * 4;
    xs[r][512+c] = v.x; xs[r][512+c+1] = v.y; xs[r][512+c+2] = v.z; xs[r][512+c+3] = v.w;
  }
  __syncthreads();

  const int o = tid * 4;
  float acc[8][4];
  float b0 = lb[o], b1 = lb[o+1], b2 = lb[o+2], b3 = lb[o+3];
  #pragma unroll
  for (int r = 0; r < 8; ++r){ acc[r][0]=b0; acc[r][1]=b1; acc[r][2]=b2; acc[r][3]=b3; }

  for (int d = 0; d < 2 * DM_; ++d){
    float4 wv = *(const float4*)(wt + (long)d * DM_ + o);
    #pragma unroll
    for (int r = 0; r < 8; ++r){
      float xd = xs[r][d];
      acc[r][0] += xd * wv.x; acc[r][1] += xd * wv.y;
      acc[r][2] += xd * wv.z; acc[r][3] += xd * wv.w;
    }
  }
  #pragma unroll
  for (int r = 0; r < 8; ++r){
    float* op = out + (long)(row0 + r) * DM_ + o;
    op[0]=acc[r][0]; op[1]=acc[r][1]; op[2]=acc[r][2]; op[3]=acc[r][3];
  }
}

// ---------------------------------------------------------------------------
// K7: fused zero + scatter of the attn output region (runs LAST).
// ---------------------------------------------------------------------------
__global__ __launch_bounds__(256) void write_attn(
    const float* __restrict__ pmax, const int* __restrict__ amax,
    float* __restrict__ attn_out){
  int row  = blockIdx.x * 4 + (threadIdx.x >> 6);
  int lane = threadIdx.x & 63;
  float p = pmax[row];
  int a = amax[row];
  float4* rowp = (float4*)(attn_out + (long)row * LQ_);
  #pragma unroll
  for (int i = 0; i < 8; ++i){
    int f4idx = i * 64 + lane;        // 512 float4s per row
    int col0  = f4idx * 4;
    float4 z = make_float4(0.f, 0.f, 0.f, 0.f);
    if (a >= col0 && a < col0 + 4){
      int r = a - col0;
      if      (r == 0) z.x = p;
      else if (r == 1) z.y = p;
      else if (r == 2) z.z = p;
      else             z.w = p;
    }
    rowp[f4idx] = z;
  }
}

// ---------------------------------------------------------------------------
extern "C" void kernel_launch(void* const* d_in, const int* in_sizes, int n_in,
                              void* d_out, int out_size, void* d_ws, size_t ws_size,
                              hipStream_t stream){
  const float* q  = (const float*)d_in[0];
  const float* k  = (const float*)d_in[1];
  const float* v  = (const float*)d_in[2];
  const float* wq = (const float*)d_in[3];
  const float* wk = (const float*)d_in[4];
  const float* wv = (const float*)d_in[5];
  const float* pw = (const float*)d_in[6];
  const float* pb = (const float*)d_in[7];
  const float* lw = (const float*)d_in[8];
  const float* lb = (const float*)d_in[9];

  float* out0     = (float*)d_out;                    // (2,2048,512)
  float* attn_out = out0 + (long)B_ * LQ_ * DM_;      // (16,2048,2048) = 67.1M floats

  // Large scratch lives INSIDE the attn output region; dead before write_attn.
  float* scr  = attn_out;
  ushort* qhb = (ushort*)scr;                          // 16*2048*64 bf16 (4 MB)
  ushort* khb = qhb + (long)HB_ * LQ_ * DK_;           // 4 MB
  float* vh   = (float*)(khb + (long)HB_ * LQ_ * DK_); // 16*2048*64 fp32 (8 MB)
  float* oh   = vh + (long)HB_ * LQ_ * DK_;            // 2*2048*512 (8 MB)
  float* y    = oh + (long)B_ * LQ_ * DM_;             // 8 MB
  float* pwT  = y  + (long)B_ * LQ_ * DM_;             // 1 MB
  float* lwT  = pwT + (long)DM_ * DM_;                 // 2 MB
  // total ~35 MB << 268 MB region

  // d_ws: only per-row stats (256 KB) — must survive write_attn.
  float* pmax = (float*)d_ws;                          // 16*2048 floats
  int*   amax = (int*)(pmax + (long)HB_ * LQ_);        // 16*2048 ints

  // weight transposes ([out][in] -> [in][out])
  transpose_w<<<(DM_*DM_ + 255)/256, 256, 0, stream>>>(pw, pwT, DM_, DM_);
  transpose_w<<<(DM_*2*DM_ + 255)/256, 256, 0, stream>>>(lw, lwT, DM_, 2*DM_);

  // per-head projections (q,k -> bf16; q pre-scaled to log2-space)
  qkv_proj<<<dim3(B_*LQ_/8, 3), 128, 0, stream>>>(q, k, v, wq, wk, wv, qhb, khb, vh);

  // MFMA scores + branch-free top-1 softmax
  attn_top1_mfma<<<dim3(HB_, LQ_/64), 256, 0, stream>>>(qhb, khb, pmax, amax);

  // gather PV rows
  gather_oh<<<HB_*LQ_/4, 256, 0, stream>>>(vh, pmax, amax, oh);

  // output projection
  proj_kernel<<<B_*LQ_/8, 128, 0, stream>>>(oh, pwT, pb, y);

  // final concat-linear -> output 0
  lin_kernel<<<B_*LQ_/8, 128, 0, stream>>>(q, y, lwT, lb, out0);

  // LAST: rewrite the whole attn region with zeros + scattered p values
  write_attn<<<HB_*LQ_/4, 256, 0, stream>>>(pmax, amax, attn_out);
}

// Round 5
// 178.724 us; speedup vs baseline: 2.8834x; 1.9942x over previous
//
#include <hip/hip_runtime.h>
#include <hip/hip_bf16.h>

// Problem constants
#define B_   2
#define LQ_  2048
#define NH_  8
#define HB_  16      // NH_*B_
#define DM_  512
#define DK_  64

// 1/sqrt(512)  (temper = sqrt(d_model), per reference)
#define INV_TEMPER 0.04419417382415922f
// folded into Q at projection time: scores come out of MFMA in log2-space
#define SCALE_T (0.04419417382415922f * 1.4426950408889634f)

typedef short s16x8 __attribute__((ext_vector_type(8)));   // 8 bf16 (4 VGPRs)
typedef float f32x4 __attribute__((ext_vector_type(4)));   // MFMA 16x16 C/D

__device__ __forceinline__ ushort f2bfbits(float f){
  __hip_bfloat16 h = __float2bfloat16(f);
  union { __hip_bfloat16 h; ushort u; } cv; cv.h = h; return cv.u;
}
__device__ __forceinline__ uint4 pack8(float4 v0, float4 v1){
  uint4 p;
  p.x = (uint)f2bfbits(v0.x) | ((uint)f2bfbits(v0.y) << 16);
  p.y = (uint)f2bfbits(v0.z) | ((uint)f2bfbits(v0.w) << 16);
  p.z = (uint)f2bfbits(v1.x) | ((uint)f2bfbits(v1.y) << 16);
  p.w = (uint)f2bfbits(v1.z) | ((uint)f2bfbits(v1.w) << 16);
  return p;
}

// ---------------------------------------------------------------------------
// K0: repack per-head weights (h,d,ko) -> fp32 [n=h*64+ko][d]  (tiny, once)
// ---------------------------------------------------------------------------
__global__ __launch_bounds__(256) void repack_w(
    const float* __restrict__ wq, const float* __restrict__ wk, const float* __restrict__ wv,
    float* __restrict__ wqT, float* __restrict__ wkT, float* __restrict__ wvT){
  const float* src = (blockIdx.y == 0) ? wq : (blockIdx.y == 1) ? wk : wv;
  float* dst       = (blockIdx.y == 0) ? wqT : (blockIdx.y == 1) ? wkT : wvT;
  int i = blockIdx.x * 256 + threadIdx.x;      // over 512*512, d fastest
  int n = i >> 9, d = i & 511;
  int h = n >> 6, ko = n & 63;
  dst[i] = src[((long)h * DM_ + d) * DK_ + ko];
}

// ---------------------------------------------------------------------------
// K1: generic bf16-MFMA GEMM, A fp32 [4096][512] row-major (cast on stage),
// Bt fp32 [N][K] row-major (weights in (out,in) layout), C per-mode.
// Block 256 thr = 4 waves, tile 64(M)x64(N), K-step 64.
// Tiles staged in LDS as bf16 [row][64k], 128B rows, XOR swizzle (row&7)<<4.
// Frag pattern identical to attn_top1_mfma (verified):
//   A/B frag: row=l15 (within 16-group), k=l4*8..+7;  C: col=l15, row=l4*4+r.
// mode 0: C=qhb bf16 head-layout, scale SCALE_T  (A=q,  Bt=wqT)
// mode 1: C=khb bf16 head-layout                 (A=k,  Bt=wkT)
// mode 2: C=vh  fp32 head-layout                 (A=v,  Bt=wvT)
// mode 3: C=y   fp32 [4096][512], +bias          (A=oh, Bt=proj_w)
// mode 4: C=out0 fp32 [4096][512], +bias, K=1024 (A=q k<512 | A2=y, Bt=lin_w)
// ---------------------------------------------------------------------------
__global__ __launch_bounds__(256) void gemm_mfma(
    const float* __restrict__ A, const float* __restrict__ A2,
    const float* __restrict__ Bt, const float* __restrict__ bias,
    void* __restrict__ Cout, int K, int mode){
  const int m0 = blockIdx.x * 64;
  const int n0 = blockIdx.y * 64;
  const int tid = threadIdx.x;
  const int wid = tid >> 6, lane = tid & 63;
  const int l15 = lane & 15, l4 = lane >> 4;

  __shared__ ushort as_[64 * 64];   // 8 KB
  __shared__ ushort bs_[64 * 64];   // 8 KB

  f32x4 acc[4];
  #pragma unroll
  for (int ct = 0; ct < 4; ++ct){ acc[ct][0]=0.f; acc[ct][1]=0.f; acc[ct][2]=0.f; acc[ct][3]=0.f; }

  for (int k0 = 0; k0 < K; k0 += 64){
    const float* Asrc = (k0 < 512) ? A : A2;   // A rows always stride 512
    const int kk = (k0 < 512) ? k0 : k0 - 512;
    __syncthreads();    // protect previous tile's reads
    for (int i = tid; i < 512; i += 256){
      int r = i >> 3, c = i & 7;               // row, 8-col group
      // A tile
      const float* sa = Asrc + (long)(m0 + r) * 512 + kk + c * 8;
      float4 a0 = *(const float4*)(sa);
      float4 a1 = *(const float4*)(sa + 4);
      *(uint4*)((char*)as_ + r * 128 + ((c * 16) ^ ((r & 7) << 4))) = pack8(a0, a1);
      // B tile
      const float* sb = Bt + (long)(n0 + r) * K + k0 + c * 8;
      float4 b0 = *(const float4*)(sb);
      float4 b1 = *(const float4*)(sb + 4);
      *(uint4*)((char*)bs_ + r * 128 + ((c * 16) ^ ((r & 7) << 4))) = pack8(b0, b1);
    }
    __syncthreads();

    const char* arow = (const char*)as_ + (wid * 16 + l15) * 128;
    const int swz = (l15 & 7) << 4;
    s16x8 a0 = *(const s16x8*)(arow + ((l4 * 16) ^ swz));
    s16x8 a1 = *(const s16x8*)(arow + ((64 + l4 * 16) ^ swz));
    #pragma unroll
    for (int ct = 0; ct < 4; ++ct){
      const char* brow = (const char*)bs_ + (ct * 16 + l15) * 128;
      s16x8 b0 = *(const s16x8*)(brow + ((l4 * 16) ^ swz));
      s16x8 b1 = *(const s16x8*)(brow + ((64 + l4 * 16) ^ swz));
      acc[ct] = __builtin_amdgcn_mfma_f32_16x16x32_bf16(a0, b0, acc[ct], 0, 0, 0);
      acc[ct] = __builtin_amdgcn_mfma_f32_16x16x32_bf16(a1, b1, acc[ct], 0, 0, 0);
    }
  }

  // epilogue
  const float scale = (mode == 0) ? SCALE_T : 1.0f;
  #pragma unroll
  for (int ct = 0; ct < 4; ++ct){
    int col = n0 + ct * 16 + l15;
    #pragma unroll
    for (int r = 0; r < 4; ++r){
      int m = m0 + wid * 16 + l4 * 4 + r;
      float val = acc[ct][r];
      if (mode <= 1){
        int b = m >> 11, l = m & 2047, h = col >> 6, ko = col & 63;
        ((ushort*)Cout)[(((long)h * B_ + b) * LQ_ + l) * DK_ + ko] = f2bfbits(val * scale);
      } else if (mode == 2){
        int b = m >> 11, l = m & 2047, h = col >> 6, ko = col & 63;
        ((float*)Cout)[(((long)h * B_ + b) * LQ_ + l) * DK_ + ko] = val;
      } else {
        ((float*)Cout)[(long)m * DM_ + col] = val + bias[col];
      }
    }
  }
}

// ---------------------------------------------------------------------------
// K2: MFMA scores + branch-free top-1 softmax stats (log2-space).
// (unchanged from round 4 — verified)
// ---------------------------------------------------------------------------
__global__ __launch_bounds__(256) void attn_top1_mfma(
    const ushort* __restrict__ qhb, const ushort* __restrict__ khb,
    float* __restrict__ pmax, int* __restrict__ amax){
  const int hb  = blockIdx.x;
  const int q0  = blockIdx.y * 64;
  const int tid = threadIdx.x;
  const int wid  = tid >> 6;
  const int lane = tid & 63;
  const int l15  = lane & 15;
  const int l4   = lane >> 4;

  __shared__ ushort ks[64 * 64];   // 8 KB, swizzled rows of 128B

  const ushort* qrow = qhb + ((long)hb * LQ_ + q0 + wid * 16 + l15) * DK_;
  s16x8 aq0 = *(const s16x8*)(qrow +  0 + l4 * 8);
  s16x8 aq1 = *(const s16x8*)(qrow + 32 + l4 * 8);

  float m[4], sum[4]; int arg[4];
  #pragma unroll
  for (int r = 0; r < 4; ++r){ m[r] = -1e30f; sum[r] = 0.f; arg[r] = 0; }

  for (int jt = 0; jt < LQ_ / 64; ++jt){
    __syncthreads();
    const ushort* kbase = khb + ((long)hb * LQ_ + jt * 64) * DK_;
    #pragma unroll
    for (int i = tid; i < 512; i += 256){
      int r = i >> 3, c = i & 7;
      uint4 val = *(const uint4*)(kbase + r * 64 + c * 8);
      *(uint4*)((char*)ks + r * 128 + ((c * 16) ^ ((r & 7) << 4))) = val;
    }
    __syncthreads();

    f32x4 acc[4];
    #pragma unroll
    for (int ct = 0; ct < 4; ++ct){
      int row = ct * 16 + l15;
      const char* base = (const char*)ks + row * 128;
      int swz = (row & 7) << 4;
      s16x8 b0 = *(const s16x8*)(base + ((l4 * 16) ^ swz));
      s16x8 b1 = *(const s16x8*)(base + ((64 + l4 * 16) ^ swz));
      f32x4 c; c[0]=0.f; c[1]=0.f; c[2]=0.f; c[3]=0.f;
      c = __builtin_amdgcn_mfma_f32_16x16x32_bf16(aq0, b0, c, 0, 0, 0);
      c = __builtin_amdgcn_mfma_f32_16x16x32_bf16(aq1, b1, c, 0, 0, 0);
      acc[ct] = c;
    }

    #pragma unroll
    for (int ct = 0; ct < 4; ++ct){
      int col = jt * 64 + ct * 16 + l15;
      #pragma unroll
      for (int r = 0; r < 4; ++r){
        float t = acc[ct][r];
        sum[r] += exp2f(t);
        bool gt = t > m[r];
        arg[r] = gt ? col : arg[r];
        m[r]   = gt ? t : m[r];
      }
    }
  }

  #pragma unroll
  for (int off = 1; off < 16; off <<= 1){
    #pragma unroll
    for (int r = 0; r < 4; ++r){
      float m2 = __shfl_xor(m[r], off);
      float s2 = __shfl_xor(sum[r], off);
      int   a2 = __shfl_xor(arg[r], off);
      sum[r] += s2;
      bool take = (m2 > m[r]) || (m2 == m[r] && a2 < arg[r]);
      arg[r] = take ? a2 : arg[r];
      m[r]   = take ? m2 : m[r];
    }
  }

  if (l15 == 0){
    #pragma unroll
    for (int r = 0; r < 4; ++r){
      long row = (long)hb * LQ_ + q0 + wid * 16 + l4 * 4 + r;
      pmax[row] = exp2f(m[r]) / sum[r];
      amax[row] = arg[r];
    }
  }
}

// ---------------------------------------------------------------------------
// K3: gather out_heads rows = pmax * vh[argmax]  (fp32 oh)
// ---------------------------------------------------------------------------
__global__ __launch_bounds__(256) void gather_oh(
    const float* __restrict__ vh, const float* __restrict__ pmax, const int* __restrict__ amax,
    float* __restrict__ oh){
  int row  = blockIdx.x * 4 + (threadIdx.x >> 6);
  int lane = threadIdx.x & 63;
  int hb = row >> 11, q = row & 2047;
  int h = hb >> 1, b = hb & 1;
  float p = pmax[row];
  int a = amax[row];
  float val = vh[((long)hb * LQ_ + a) * DK_ + lane];
  oh[((long)(b * LQ_ + q)) * DM_ + h * DK_ + lane] = p * val;
}

// ---------------------------------------------------------------------------
// K4: fused zero + scatter of the attn output region (runs LAST).
// ---------------------------------------------------------------------------
__global__ __launch_bounds__(256) void write_attn(
    const float* __restrict__ pmax, const int* __restrict__ amax,
    float* __restrict__ attn_out){
  int row  = blockIdx.x * 4 + (threadIdx.x >> 6);
  int lane = threadIdx.x & 63;
  float p = pmax[row];
  int a = amax[row];
  float4* rowp = (float4*)(attn_out + (long)row * LQ_);
  #pragma unroll
  for (int i = 0; i < 8; ++i){
    int f4idx = i * 64 + lane;        // 512 float4s per row
    int col0  = f4idx * 4;
    float4 z = make_float4(0.f, 0.f, 0.f, 0.f);
    if (a >= col0 && a < col0 + 4){
      int r = a - col0;
      if      (r == 0) z.x = p;
      else if (r == 1) z.y = p;
      else if (r == 2) z.z = p;
      else             z.w = p;
    }
    rowp[f4idx] = z;
  }
}

// ---------------------------------------------------------------------------
extern "C" void kernel_launch(void* const* d_in, const int* in_sizes, int n_in,
                              void* d_out, int out_size, void* d_ws, size_t ws_size,
                              hipStream_t stream){
  const float* q  = (const float*)d_in[0];
  const float* k  = (const float*)d_in[1];
  const float* v  = (const float*)d_in[2];
  const float* wq = (const float*)d_in[3];
  const float* wk = (const float*)d_in[4];
  const float* wv = (const float*)d_in[5];
  const float* pw = (const float*)d_in[6];
  const float* pb = (const float*)d_in[7];
  const float* lw = (const float*)d_in[8];
  const float* lb = (const float*)d_in[9];

  float* out0     = (float*)d_out;                    // (2,2048,512)
  float* attn_out = out0 + (long)B_ * LQ_ * DM_;      // (16,2048,2048) = 67.1M floats

  // Scratch lives INSIDE the attn output region; all dead before write_attn.
  float* vh   = attn_out;                             // 2M floats (8 MB)
  float* oh   = vh  + (long)HB_ * LQ_ * DK_;          // 2M floats (8 MB)
  float* y    = oh  + (long)B_ * LQ_ * DM_;           // 2M floats (8 MB)
  float* wqT  = y   + (long)B_ * LQ_ * DM_;           // 256K floats
  float* wkT  = wqT + (long)DM_ * DM_ / 2 * 2;        // 256K floats
  float* wvT  = wkT + (long)DM_ * DM_;                // (DM*DM = 262144)
  ushort* qhb = (ushort*)(wvT + (long)DM_ * DM_);     // 2M bf16 (4 MB)
  ushort* khb = qhb + (long)HB_ * LQ_ * DK_;          // 2M bf16 (4 MB)
  // total ~36.7 MB << 268 MB region

  // d_ws: only per-row stats (256 KB) — must survive write_attn.
  float* pmax = (float*)d_ws;                          // 16*2048 floats
  int*   amax = (int*)(pmax + (long)HB_ * LQ_);        // 16*2048 ints

  // repack per-head weights to [n][d] fp32
  repack_w<<<dim3(DM_*DM_/256, 3), 256, 0, stream>>>(wq, wk, wv, wqT, wkT, wvT);

  // head projections via MFMA GEMM
  gemm_mfma<<<dim3(64, 8), 256, 0, stream>>>(q, q, wqT, nullptr, qhb, DM_, 0);
  gemm_mfma<<<dim3(64, 8), 256, 0, stream>>>(k, k, wkT, nullptr, khb, DM_, 1);
  gemm_mfma<<<dim3(64, 8), 256, 0, stream>>>(v, v, wvT, nullptr, vh,  DM_, 2);

  // MFMA scores + branch-free top-1 softmax
  attn_top1_mfma<<<dim3(HB_, LQ_/64), 256, 0, stream>>>(qhb, khb, pmax, amax);

  // gather PV rows (fp32 oh)
  gather_oh<<<HB_*LQ_/4, 256, 0, stream>>>(vh, pmax, amax, oh);

  // output projection: y = oh @ proj_w.T + pb   (proj_w natively [N][K])
  gemm_mfma<<<dim3(64, 8), 256, 0, stream>>>(oh, oh, pw, pb, y, DM_, 3);

  // final concat-linear: out0 = [q|y] @ lin_w.T + lb   (K=1024)
  gemm_mfma<<<dim3(64, 8), 256, 0, stream>>>(q, y, lw, lb, out0, 2*DM_, 4);

  // LAST: rewrite the whole attn region with zeros + scattered p values
  write_attn<<<HB_*LQ_/4, 256, 0, stream>>>(pmax, amax, attn_out);
}